// Round 6
// baseline (5298.828 us; speedup 1.0000x reference)
//
#include <hip/hip_runtime.h>

typedef _Float16 half8 __attribute__((ext_vector_type(8)));
typedef _Float16 half4 __attribute__((ext_vector_type(4)));
typedef float f32x4 __attribute__((ext_vector_type(4)));

#define NSTEP 48
#define MT 16          // batch rows per workgroup (256 wgs cover 4096)
#define W0S 544        // W0 packed row stride: 256 x-feat | 256 h0 | 3 notes | 29 zero pad
#define W1S 512        // W1 packed row stride: 256 h0new | 256 h1
#define LDX 552        // lds_h0 row stride (fp16): [x 256 | h0 256 | sn 3 | 0s]; 1104 B = 69*16 -> odd x16B
#define LDH1 264       // lds_h1 row stride; 528 B = 33*16 -> odd x16B

__device__ __forceinline__ float sigm(float x) { return 1.0f / (1.0f + __expf(-x)); }
__device__ __forceinline__ float tanh_f(float x) {
  float ax = fabsf(x);
  float e = __expf(-2.0f * ax);
  float t = (1.0f - e) / (1.0f + e);
  return copysignf(t, x);
}

__global__ void prep_weights(const float* __restrict__ Wih0, const float* __restrict__ Whh0,
                             const float* __restrict__ bih0, const float* __restrict__ bhh0,
                             const float* __restrict__ Wih1, const float* __restrict__ Whh1,
                             const float* __restrict__ bih1, const float* __restrict__ bhh1,
                             _Float16* __restrict__ W0h, _Float16* __restrict__ W1h,
                             float* __restrict__ b0, float* __restrict__ b1) {
  int n = blockIdx.x;      // 1024
  int k = threadIdx.x;     // 256
  W0h[n * W0S + k]       = (_Float16)Wih0[n * 259 + k];
  W0h[n * W0S + 256 + k] = (_Float16)Whh0[n * 256 + k];
  if (k < 32) W0h[n * W0S + 512 + k] = (k < 3) ? (_Float16)Wih0[n * 259 + 256 + k] : (_Float16)0.0f;
  W1h[n * W1S + k]       = (_Float16)Wih1[n * 256 + k];
  W1h[n * W1S + 256 + k] = (_Float16)Whh1[n * 256 + k];
  if (k == 0) { b0[n] = bih0[n] + bhh0[n]; b1[n] = bih1[n] + bhh1[n]; }
}

// 1024 threads = 16 waves; wave v owns units [v*16, v*16+16); all waves share batch rows [row0, row0+16).
// HW fact (r3-r5): 1024-thr wg => 16 waves co-resident => 4 waves/SIMD => 128 regs/wave = 64 arch VGPR + 64 AGPR.
// Arch-VGPR plan: B0f+B1f 32 + A 4 + addr/misc ~14 -> ~50, fits 64. acc/c-state live in AGPRs.
__global__ __launch_bounds__(1024, 4)
void noteaxis_main(const float* __restrict__ nf, const float* __restrict__ cond,
                   const _Float16* __restrict__ W0h, const _Float16* __restrict__ W1h,
                   const float* __restrict__ b0g, const float* __restrict__ b1g,
                   const float* __restrict__ Wout, const float* __restrict__ bout,
                   float* __restrict__ out) {
  __shared__ __align__(16) _Float16 lds_h0[MT][LDX];   // [x | h0 | sn | 0s]
  __shared__ __align__(16) _Float16 lds_h1[MT][LDH1];
  __shared__ float lds_b0[1024];
  __shared__ float lds_b1[1024];
  __shared__ float lds_part[16][MT][3];

  const int tid = threadIdx.x;
  const int v = tid >> 6;
  const int lane = tid & 63;
  const int r = lane & 15;
  const int q = lane >> 4;
  const int row0 = blockIdx.x * MT;
  const int u0 = v * 16 + r;

  for (int i = tid; i < MT * LDX; i += 1024) ((_Float16*)lds_h0)[i] = (_Float16)0.0f;
  for (int i = tid; i < MT * LDH1; i += 1024) ((_Float16*)lds_h1)[i] = (_Float16)0.0f;
  lds_b0[tid] = b0g[tid];
  lds_b1[tid] = b1g[tid];

  const _Float16* pB0 = W0h + (size_t)u0 * W0S + q * 8;
  const _Float16* pB1 = W1h + (size_t)u0 * W1S + q * 8;
  const float* pX = nf + ((size_t)(row0 + v) * NSTEP) * 256 + (lane << 2);

  const float wo0 = Wout[0 * 256 + u0];
  const float wo1 = Wout[1 * 256 + u0];
  const float wo2 = Wout[2 * 256 + u0];
  const float bo0 = bout[0], bo1 = bout[1], bo2 = bout[2];

  float c0s[4], c1s[4];
#pragma unroll
  for (int g = 0; g < 4; ++g) { c0s[g] = 0.0f; c1s[g] = 0.0f; }

  f32x4 acc[4];
  half8 B0f[4], B1f[4];          // single-kt double buffers: 16+16 = 32 arch VGPRs

#define LOADB0(D, KT)                                                                   \
  {                                                                                     \
    _Pragma("unroll")                                                                   \
    for (int c = 0; c < 4; ++c)                                                         \
      D[c] = *(const half8*)(pB0 + (size_t)c * (256 * W0S) + (KT) * 32);                \
  }
#define LOADB1(D, KT)                                                                   \
  {                                                                                     \
    _Pragma("unroll")                                                                   \
    for (int c = 0; c < 4; ++c)                                                         \
      D[c] = *(const half8*)(pB1 + (size_t)c * (256 * W1S) + (KT) * 32);                \
  }
#define MFMA4(A, B)                                                                     \
  {                                                                                     \
    _Pragma("unroll")                                                                   \
    for (int c = 0; c < 4; ++c)                                                         \
      acc[c] = __builtin_amdgcn_mfma_f32_16x16x32_f16((A), (B)[c], acc[c], 0, 0, 0);    \
  }
#define A0(KT) (*(const half8*)&lds_h0[r][(KT) * 32 + q * 8])
#define A1(KT) ((KT) < 8 ? *(const half8*)&lds_h0[r][256 + (KT) * 32 + q * 8]           \
                         : *(const half8*)&lds_h1[r][((KT) - 8) * 32 + q * 8])

// one kt of L0: consume CUR, prefetch kt NKT into NXT
#define G0(CUR, NXT, KT, NKT) { half8 a = A0(KT); LOADB0(NXT, NKT); MFMA4(a, CUR); }
// last L0 kt (16): prefetch L1 kt0 into NXT
#define G0X(CUR, NXT)         { half8 a = A0(16); LOADB1(NXT, 0);   MFMA4(a, CUR); }
#define G1(CUR, NXT, KT, NKT) { half8 a = A1(KT); LOADB1(NXT, NKT); MFMA4(a, CUR); }
// last L1 kt (15): prefetch next step's L0 kt0 into NXT
#define G1X(CUR, NXT)         { half8 a = A1(15); LOADB0(NXT, 0);   MFMA4(a, CUR); }

// One full LSTM step. SB holds L0-kt0 on entry; on exit OB holds next step's L0-kt0.
#define STEP(SB, OB, N)                                                                 \
  {                                                                                     \
    const int n = (N);                                                                  \
    {                                                                                   \
      const float4 xf = *(const float4*)(pX + (size_t)n * 256);                         \
      half4 h4;                                                                         \
      h4[0] = (_Float16)xf.x; h4[1] = (_Float16)xf.y;                                   \
      h4[2] = (_Float16)xf.z; h4[3] = (_Float16)xf.w;                                   \
      *(half4*)&lds_h0[v][lane << 2] = h4;                                              \
    }                                                                                   \
    if (tid < MT) {                                                                     \
      float s0 = 0.f, s1 = 0.f, s2 = 0.f;                                               \
      if (n > 0) {                                                                      \
        const float* cp = cond + ((size_t)(row0 + tid) * NSTEP + (n - 1)) * 3;          \
        s0 = cp[0]; s1 = cp[1]; s2 = cp[2];                                             \
      }                                                                                 \
      lds_h0[tid][512] = (_Float16)s0;                                                  \
      lds_h0[tid][513] = (_Float16)s1;                                                  \
      lds_h0[tid][514] = (_Float16)s2;                                                  \
    }                                                                                   \
    __syncthreads();  /* B0 */                                                          \
    _Pragma("unroll")                                                                   \
    for (int c = 0; c < 4; ++c) {                                                       \
      float b = lds_b0[c * 256 + u0];                                                   \
      f32x4 bz = {b, b, b, b};                                                          \
      acc[c] = bz;                                                                      \
    }                                                                                   \
    G0(SB, OB, 0, 1)   G0(OB, SB, 1, 2)   G0(SB, OB, 2, 3)   G0(OB, SB, 3, 4)           \
    G0(SB, OB, 4, 5)   G0(OB, SB, 5, 6)   G0(SB, OB, 6, 7)   G0(OB, SB, 7, 8)           \
    G0(SB, OB, 8, 9)   G0(OB, SB, 9, 10)  G0(SB, OB, 10, 11) G0(OB, SB, 11, 12)         \
    G0(SB, OB, 12, 13) G0(OB, SB, 13, 14) G0(SB, OB, 14, 15) G0(OB, SB, 15, 16)         \
    G0X(SB, OB)                                                                         \
    __syncthreads();  /* B1: done reading lds_h0 (x, h0(n-1), sn) */                    \
    _Pragma("unroll")                                                                   \
    for (int g = 0; g < 4; ++g) {                                                       \
      float i_ = acc[0][g], f_ = acc[1][g], g_ = acc[2][g], o_ = acc[3][g];             \
      float cc = sigm(f_) * c0s[g] + sigm(i_) * tanh_f(g_);                             \
      c0s[g] = cc;                                                                      \
      lds_h0[q * 4 + g][256 + u0] = (_Float16)(sigm(o_) * tanh_f(cc));                  \
    }                                                                                   \
    __syncthreads();  /* B2: h0(n) visible */                                           \
    _Pragma("unroll")                                                                   \
    for (int c = 0; c < 4; ++c) {                                                       \
      float b = lds_b1[c * 256 + u0];                                                   \
      f32x4 bz = {b, b, b, b};                                                          \
      acc[c] = bz;                                                                      \
    }                                                                                   \
    G1(OB, SB, 0, 1)   G1(SB, OB, 1, 2)   G1(OB, SB, 2, 3)   G1(SB, OB, 3, 4)           \
    G1(OB, SB, 4, 5)   G1(SB, OB, 5, 6)   G1(OB, SB, 6, 7)   G1(SB, OB, 7, 8)           \
    G1(OB, SB, 8, 9)   G1(SB, OB, 9, 10)  G1(OB, SB, 10, 11) G1(SB, OB, 11, 12)         \
    G1(OB, SB, 12, 13) G1(SB, OB, 13, 14) G1(OB, SB, 14, 15)                            \
    G1X(SB, OB)                                                                         \
    __syncthreads();  /* B3: done reading lds_h0/lds_h1 */                              \
    {                                                                                   \
      float part[4][3];                                                                 \
      _Pragma("unroll")                                                                 \
      for (int g = 0; g < 4; ++g) {                                                     \
        float i_ = acc[0][g], f_ = acc[1][g], g_ = acc[2][g], o_ = acc[3][g];           \
        float cc = sigm(f_) * c1s[g] + sigm(i_) * tanh_f(g_);                           \
        c1s[g] = cc;                                                                    \
        float hh = sigm(o_) * tanh_f(cc);                                               \
        lds_h1[q * 4 + g][u0] = (_Float16)hh;                                           \
        part[g][0] = hh * wo0;                                                          \
        part[g][1] = hh * wo1;                                                          \
        part[g][2] = hh * wo2;                                                          \
      }                                                                                 \
      _Pragma("unroll")                                                                 \
      for (int g = 0; g < 4; ++g)                                                       \
        _Pragma("unroll")                                                               \
        for (int ch = 0; ch < 3; ++ch) {                                                \
          float p = part[g][ch];                                                        \
          p += __shfl_xor(p, 1);                                                        \
          p += __shfl_xor(p, 2);                                                        \
          p += __shfl_xor(p, 4);                                                        \
          p += __shfl_xor(p, 8);                                                        \
          part[g][ch] = p;                                                              \
        }                                                                               \
      if (r == 0) {                                                                     \
        _Pragma("unroll")                                                               \
        for (int g = 0; g < 4; ++g) {                                                   \
          int m = q * 4 + g;                                                            \
          lds_part[v][m][0] = part[g][0];                                               \
          lds_part[v][m][1] = part[g][1];                                               \
          lds_part[v][m][2] = part[g][2];                                               \
        }                                                                               \
      }                                                                                 \
    }                                                                                   \
    __syncthreads();  /* B4 */                                                          \
    if (tid < MT * 3) {                                                                 \
      int m = tid / 3;                                                                  \
      int ch = tid - m * 3;                                                             \
      float s = (ch == 0 ? bo0 : (ch == 1 ? bo1 : bo2));                                \
      _Pragma("unroll")                                                                 \
      for (int w = 0; w < 16; ++w) s += lds_part[w][m][ch];                             \
      if (ch < 2) s = 1.0f / (1.0f + __expf(-s));                                       \
      out[((size_t)(row0 + m) * NSTEP + n) * 3 + ch] = s;                               \
    }                                                                                   \
  }

  __syncthreads();
  LOADB0(B0f, 0);                // prologue: L0 kt0 for step 0

#pragma unroll 1
  for (int n2 = 0; n2 < NSTEP / 2; ++n2) {
    STEP(B0f, B1f, 2 * n2)       // consumes 33 kts -> parity flips
    STEP(B1f, B0f, 2 * n2 + 1)   // flips back -> loop is parity-consistent
  }
}

extern "C" void kernel_launch(void* const* d_in, const int* in_sizes, int n_in,
                              void* d_out, int out_size, void* d_ws, size_t ws_size,
                              hipStream_t stream) {
  const float* nf   = (const float*)d_in[0];
  const float* cond = (const float*)d_in[1];
  const float* Wih0 = (const float*)d_in[2];
  const float* Whh0 = (const float*)d_in[3];
  const float* bih0 = (const float*)d_in[4];
  const float* bhh0 = (const float*)d_in[5];
  const float* Wih1 = (const float*)d_in[6];
  const float* Whh1 = (const float*)d_in[7];
  const float* bih1 = (const float*)d_in[8];
  const float* bhh1 = (const float*)d_in[9];
  const float* Wout = (const float*)d_in[10];
  const float* bout = (const float*)d_in[11];
  float* out = (float*)d_out;

  _Float16* W0h = (_Float16*)d_ws;                       // 1024*544*2 B
  _Float16* W1h = W0h + 1024 * W0S;                      // 1024*512*2 B
  float* b0 = (float*)(W1h + 1024 * W1S);                // 4 KB
  float* b1 = b0 + 1024;                                 // 4 KB

  prep_weights<<<1024, 256, 0, stream>>>(Wih0, Whh0, bih0, bhh0, Wih1, Whh1, bih1, bhh1, W0h, W1h, b0, b1);
  noteaxis_main<<<256, 1024, 0, stream>>>(nf, cond, W0h, W1h, b0, b1, Wout, bout, out);
}

// Round 7
// 3694.242 us; speedup vs baseline: 1.4343x; 1.4343x over previous
//
#include <hip/hip_runtime.h>

typedef _Float16 half8 __attribute__((ext_vector_type(8)));
typedef _Float16 half4 __attribute__((ext_vector_type(4)));
typedef float f32x4 __attribute__((ext_vector_type(4)));

#define NSTEP 48
#define MT 16          // batch rows per workgroup; 256 wgs cover 4096
#define LDX 552        // lds_h0 row stride (fp16): [x 256 | h0 256 | sn 3 | pad]
#define LDH1 264       // lds_h1 row stride

// Weight stream: 66 granules of 32768 B, in exact consumption order.
// granule g layout: [wave v:16][frag j:2][lane l:64][16 B]  (wave v's 2 KB slice is self-staged & self-consumed)
// frag element [l][i] = W[row = c*256 + v*16 + (l&15)][col = kt*32 + (l>>4)*8 + i]
//   g in [0,34):  layer0, kt = g>>1,      gates c = (g&1)*2 + j; cols: [0,256)=W_ih0 feat, [256,512)=W_hh0, [512,515)=notes, rest 0
//   g in [34,66): layer1, kt = (g-34)>>1, gates c = ((g-34)&1)*2 + j; cols: [0,256)=W_ih1, [256,512)=W_hh1

__device__ __forceinline__ float sigm(float x) { return 1.0f / (1.0f + __expf(-x)); }
__device__ __forceinline__ float tanh_f(float x) {
  float ax = fabsf(x);
  float e = __expf(-2.0f * ax);
  float t = (1.0f - e) / (1.0f + e);
  return copysignf(t, x);
}

__global__ void prep_weights(const float* __restrict__ Wih0, const float* __restrict__ Whh0,
                             const float* __restrict__ bih0, const float* __restrict__ bhh0,
                             const float* __restrict__ Wih1, const float* __restrict__ Whh1,
                             const float* __restrict__ bih1, const float* __restrict__ bhh1,
                             _Float16* __restrict__ stream, float* __restrict__ b0, float* __restrict__ b1) {
  int g = blockIdx.x;         // 0..65 granules, 66 = biases
  int t = threadIdx.x;        // 256
  if (g == 66) {
    for (int i = t; i < 1024; i += 256) { b0[i] = bih0[i] + bhh0[i]; b1[i] = bih1[i] + bhh1[i]; }
    return;
  }
  _Float16* dst = stream + (size_t)g * 16384;
  for (int e = t; e < 16384; e += 256) {
    int v = e >> 10, rest = e & 1023;
    int j = rest >> 9, le = rest & 511;
    int l = le >> 3, i = le & 7;
    int rr = l & 15, q = l >> 4;
    int col, row;
    float val;
    if (g < 34) {
      int kt = g >> 1, c = (g & 1) * 2 + j;
      row = c * 256 + v * 16 + rr;
      col = kt * 32 + q * 8 + i;
      if (col < 256) val = Wih0[row * 259 + col];
      else if (col < 512) val = Whh0[row * 256 + (col - 256)];
      else if (col < 515) val = Wih0[row * 259 + 256 + (col - 512)];
      else val = 0.0f;
    } else {
      int g2 = g - 34;
      int kt = g2 >> 1, c = (g2 & 1) * 2 + j;
      row = c * 256 + v * 16 + rr;
      col = kt * 32 + q * 8 + i;
      val = (col < 256) ? Wih1[row * 256 + col] : Whh1[row * 256 + (col - 256)];
    }
    dst[e] = (_Float16)val;
  }
}

// 1024 threads = 16 waves; wave v owns units [v*16, v*16+16) and batch-row v's x staging.
// B operand never touches registers: DMA'd via global_load_lds into a 3-slot LDS ring, per-wave pipelined.
__global__ __launch_bounds__(1024)
void noteaxis_main(const float* __restrict__ nf, const float* __restrict__ cond,
                   const _Float16* __restrict__ stream,
                   const float* __restrict__ b0g, const float* __restrict__ b1g,
                   const float* __restrict__ Wout, const float* __restrict__ bout,
                   float* __restrict__ out) {
  __shared__ __align__(16) _Float16 lds_s[3 * 16384];     // 96 KB weight ring (3 slots x 32 KB)
  __shared__ __align__(16) _Float16 lds_h0[MT][LDX];      // [x | h0 | sn]
  __shared__ __align__(16) _Float16 lds_h1[MT][LDH1];
  __shared__ float lds_b0[1024];
  __shared__ float lds_b1[1024];
  __shared__ float lds_part[16][MT][3];

  const int tid = threadIdx.x;
  const int v = tid >> 6;
  const int lane = tid & 63;
  const int r = lane & 15;
  const int q = lane >> 4;
  const int row0 = blockIdx.x * MT;
  const int u0 = v * 16 + r;

  for (int i = tid; i < MT * LDX; i += 1024) ((_Float16*)lds_h0)[i] = (_Float16)0.0f;
  for (int i = tid; i < MT * LDH1; i += 1024) ((_Float16*)lds_h1)[i] = (_Float16)0.0f;
  lds_b0[tid] = b0g[tid];
  lds_b1[tid] = b1g[tid];

  const float* pX = nf + ((size_t)(row0 + v) * NSTEP) * 256 + (lane << 2);
  const float wo0 = Wout[0 * 256 + u0];
  const float wo1 = Wout[1 * 256 + u0];
  const float wo2 = Wout[2 * 256 + u0];
  const float bo0 = bout[0], bo1 = bout[1], bo2 = bout[2];

  float c0s[4], c1s[4];
#pragma unroll
  for (int g = 0; g < 4; ++g) { c0s[g] = 0.0f; c1s[g] = 0.0f; }

  f32x4 acc[4];

  // Stage granule G (global stream) into ring slot S: wave v moves its own 2 KB (2 x 1 KB DMA).
#define STAGE(G, S)                                                                        \
  {                                                                                        \
    const _Float16* s_ = stream + (size_t)(G) * 16384 + (v << 10) + (lane << 3);           \
    _Float16* d_ = &lds_s[(S) * 16384 + (v << 10)];                                        \
    __builtin_amdgcn_global_load_lds((const __attribute__((address_space(1))) void*)s_,    \
                                     (__attribute__((address_space(3))) void*)d_, 16, 0, 0); \
    __builtin_amdgcn_global_load_lds((const __attribute__((address_space(1))) void*)(s_ + 512), \
                                     (__attribute__((address_space(3))) void*)(d_ + 512), 16, 0, 0); \
  }
  // wait until at most the 2 most-recent vmem ops are outstanding (robust to stray x/cond/out ops)
#define WAITVM2() __builtin_amdgcn_s_waitcnt(0x0F72)

#define BFR(S, J) (*(const half8*)&lds_s[(S) * 16384 + (v << 10) + (J) * 512 + (lane << 3)])
#define A0F(KT) (*(const half8*)&lds_h0[r][(KT) * 32 + q * 8])
#define A1F(KT) ((KT) < 8 ? *(const half8*)&lds_h0[r][256 + (KT) * 32 + q * 8]             \
                          : *(const half8*)&lds_h1[r][((KT) - 8) * 32 + q * 8])

  // granule G of layer0 (G in 0..33): kt = G>>1, gates = (G&1)*2 + {0,1}
#define G0(G)                                                                              \
  {                                                                                        \
    STAGE(((G) + 2) % 66, ((G) + 2) % 3);                                                  \
    WAITVM2();                                                                             \
    half8 a_ = A0F((G) >> 1);                                                              \
    half8 bA_ = BFR((G) % 3, 0);                                                           \
    half8 bB_ = BFR((G) % 3, 1);                                                           \
    acc[((G) & 1) * 2 + 0] = __builtin_amdgcn_mfma_f32_16x16x32_f16(a_, bA_, acc[((G) & 1) * 2 + 0], 0, 0, 0); \
    acc[((G) & 1) * 2 + 1] = __builtin_amdgcn_mfma_f32_16x16x32_f16(a_, bB_, acc[((G) & 1) * 2 + 1], 0, 0, 0); \
  }
  // granule G of layer1 (G in 34..65): kt = (G-34)>>1, gates = ((G-34)&1)*2 + {0,1}
#define G1(G)                                                                              \
  {                                                                                        \
    STAGE(((G) + 2) % 66, ((G) + 2) % 3);                                                  \
    WAITVM2();                                                                             \
    half8 a_ = A1F(((G) - 34) >> 1);                                                       \
    half8 bA_ = BFR((G) % 3, 0);                                                           \
    half8 bB_ = BFR((G) % 3, 1);                                                           \
    acc[(((G) - 34) & 1) * 2 + 0] = __builtin_amdgcn_mfma_f32_16x16x32_f16(a_, bA_, acc[(((G) - 34) & 1) * 2 + 0], 0, 0, 0); \
    acc[(((G) - 34) & 1) * 2 + 1] = __builtin_amdgcn_mfma_f32_16x16x32_f16(a_, bB_, acc[(((G) - 34) & 1) * 2 + 1], 0, 0, 0); \
  }

  STAGE(0, 0)        // prologue: granules 0,1 for step 0
  STAGE(1, 1)
  __syncthreads();

#pragma unroll 1
  for (int n = 0; n < NSTEP; ++n) {
    // ---- stage x (fp32->fp16) into lds_h0 cols [0,256); wave v handles batch row v ----
    {
      const float4 xf = *(const float4*)(pX + (size_t)n * 256);
      half4 h4;
      h4[0] = (_Float16)xf.x; h4[1] = (_Float16)xf.y; h4[2] = (_Float16)xf.z; h4[3] = (_Float16)xf.w;
      *(half4*)&lds_h0[v][lane << 2] = h4;
    }
    if (tid < MT) {
      float s0 = 0.f, s1 = 0.f, s2 = 0.f;
      if (n > 0) {
        const float* cp = cond + ((size_t)(row0 + tid) * NSTEP + (n - 1)) * 3;
        s0 = cp[0]; s1 = cp[1]; s2 = cp[2];
      }
      lds_h0[tid][512] = (_Float16)s0;
      lds_h0[tid][513] = (_Float16)s1;
      lds_h0[tid][514] = (_Float16)s2;
    }
    __syncthreads();  // B0

    // ---- Layer 0: 34 granules (17 kts x 2 gate-pairs) ----
#pragma unroll
    for (int c = 0; c < 4; ++c) {
      float b = lds_b0[c * 256 + u0];
      f32x4 bz = {b, b, b, b};
      acc[c] = bz;
    }
    G0(0)  G0(1)  G0(2)  G0(3)  G0(4)  G0(5)  G0(6)  G0(7)
    G0(8)  G0(9)  G0(10) G0(11) G0(12) G0(13) G0(14) G0(15)
    G0(16) G0(17) G0(18) G0(19) G0(20) G0(21) G0(22) G0(23)
    G0(24) G0(25) G0(26) G0(27) G0(28) G0(29) G0(30) G0(31)
    G0(32) G0(33)
    __syncthreads();  // B1: all waves done reading lds_h0 (x, h0(n-1), sn)

    // ---- cell 0: write h0(n) into lds_h0 cols [256,512) ----
#pragma unroll
    for (int g = 0; g < 4; ++g) {
      float i_ = acc[0][g], f_ = acc[1][g], g_ = acc[2][g], o_ = acc[3][g];
      float cc = sigm(f_) * c0s[g] + sigm(i_) * tanh_f(g_);
      c0s[g] = cc;
      lds_h0[q * 4 + g][256 + u0] = (_Float16)(sigm(o_) * tanh_f(cc));
    }
    __syncthreads();  // B2: h0(n) visible

    // ---- Layer 1: 32 granules (16 kts x 2 gate-pairs) ----
#pragma unroll
    for (int c = 0; c < 4; ++c) {
      float b = lds_b1[c * 256 + u0];
      f32x4 bz = {b, b, b, b};
      acc[c] = bz;
    }
    G1(34) G1(35) G1(36) G1(37) G1(38) G1(39) G1(40) G1(41)
    G1(42) G1(43) G1(44) G1(45) G1(46) G1(47) G1(48) G1(49)
    G1(50) G1(51) G1(52) G1(53) G1(54) G1(55) G1(56) G1(57)
    G1(58) G1(59) G1(60) G1(61) G1(62) G1(63) G1(64) G1(65)
    __syncthreads();  // B3: all waves done reading lds_h0/lds_h1

    // ---- cell 1 + output-projection partials ----
    float part[4][3];
#pragma unroll
    for (int g = 0; g < 4; ++g) {
      float i_ = acc[0][g], f_ = acc[1][g], g_ = acc[2][g], o_ = acc[3][g];
      float cc = sigm(f_) * c1s[g] + sigm(i_) * tanh_f(g_);
      c1s[g] = cc;
      float hh = sigm(o_) * tanh_f(cc);
      lds_h1[q * 4 + g][u0] = (_Float16)hh;
      part[g][0] = hh * wo0;
      part[g][1] = hh * wo1;
      part[g][2] = hh * wo2;
    }
#pragma unroll
    for (int g = 0; g < 4; ++g)
#pragma unroll
      for (int ch = 0; ch < 3; ++ch) {
        float p = part[g][ch];
        p += __shfl_xor(p, 1);
        p += __shfl_xor(p, 2);
        p += __shfl_xor(p, 4);
        p += __shfl_xor(p, 8);
        part[g][ch] = p;
      }
    if (r == 0) {
#pragma unroll
      for (int g = 0; g < 4; ++g) {
        int m = q * 4 + g;
        lds_part[v][m][0] = part[g][0];
        lds_part[v][m][1] = part[g][1];
        lds_part[v][m][2] = part[g][2];
      }
    }
    __syncthreads();  // B4

    if (tid < MT * 3) {
      int m = tid / 3;
      int ch = tid - m * 3;
      float s = (ch == 0 ? bo0 : (ch == 1 ? bo1 : bo2));
#pragma unroll
      for (int w = 0; w < 16; ++w) s += lds_part[w][m][ch];
      if (ch < 2) s = 1.0f / (1.0f + __expf(-s));
      out[((size_t)(row0 + m) * NSTEP + n) * 3 + ch] = s;
    }
  }
}

extern "C" void kernel_launch(void* const* d_in, const int* in_sizes, int n_in,
                              void* d_out, int out_size, void* d_ws, size_t ws_size,
                              hipStream_t stream_) {
  const float* nf   = (const float*)d_in[0];
  const float* cond = (const float*)d_in[1];
  const float* Wih0 = (const float*)d_in[2];
  const float* Whh0 = (const float*)d_in[3];
  const float* bih0 = (const float*)d_in[4];
  const float* bhh0 = (const float*)d_in[5];
  const float* Wih1 = (const float*)d_in[6];
  const float* Whh1 = (const float*)d_in[7];
  const float* bih1 = (const float*)d_in[8];
  const float* bhh1 = (const float*)d_in[9];
  const float* Wout = (const float*)d_in[10];
  const float* bout = (const float*)d_in[11];
  float* out = (float*)d_out;

  _Float16* wstream = (_Float16*)d_ws;                   // 66*16384 fp16 = 2,162,688 B
  float* b0 = (float*)((char*)d_ws + 66 * 16384 * 2);    // 4 KB
  float* b1 = b0 + 1024;                                 // 4 KB

  prep_weights<<<67, 256, 0, stream_>>>(Wih0, Whh0, bih0, bhh0, Wih1, Whh1, bih1, bhh1, wstream, b0, b1);
  noteaxis_main<<<256, 1024, 0, stream_>>>(nf, cond, wstream, b0, b1, Wout, bout, out);
}